// Round 10
// baseline (129.151 us; speedup 1.0000x reference)
//
#include <hip/hip_runtime.h>
#include <stdint.h>

// Problem constants (from reference setup_inputs)
#define NBOX 256
#define NC   32
#define ND   64
#define NH   64
#define NW   64
#define CD   16
#define CH   16
#define CW   16
#define NXCD 8
#define DHW  (ND * NH * NW)
// LDS: 2 buffers x 16 rows x 64 floats = 8192 B.
// Row yo of buffer holds the (z,y)-PRE-COMBINED source row for output row yo:
//   comb[x] = w00*I[z0,y0(yo),x] + w01*I[z0,y1(yo),x]
//           + w10*I[z1,y0(yo),x] + w11*I[z1,y1(yo),x]
// (fz block-uniform, fy per-yo -> weights are staging-thread-local).
// Stager == consumer (same 16-lane q-group) -> no barriers needed for
// correctness; one bare s_barrier per channel kept as phase governor
// (R9 lesson: free-running waves de-phase blocks and raise FETCH).

// ---- pre-kernel: stable counting-sort permutation of boxes by box_ind ----
__global__ __launch_bounds__(NBOX) void CropAndResize3D_perm_kernel(
    const int* __restrict__ box_ind, int* __restrict__ perm)
{
    __shared__ int nsh[NBOX];
    const int t = threadIdx.x;
    nsh[t] = box_ind[t];
    __syncthreads();
    const int n_t = nsh[t];
    int rank = 0;
    #pragma unroll 8
    for (int j = 0; j < NBOX; ++j) {
        const int n_j = nsh[j];
        rank += (n_j < n_t) || (n_j == n_t && j < t);
    }
    perm[rank] = t;
}

__global__ __launch_bounds__(256) void CropAndResize3D_89481348645400_kernel(
    const float* __restrict__ image,   // (N, C, D, H, W)
    const float* __restrict__ boxes,   // (NB, 6) = x1,y1,z1,x2,y2,z2
    const int*   __restrict__ box_ind, // (NB,)
    const int*   __restrict__ perm,    // (NB,) or null -> identity
    float*       __restrict__ out)     // (NB, C, CD, CH, CW)
{
    __shared__ float sh[2 * 16 * 64];  // 8 KB

    // XCD-aware swizzle (R1) + image-sorted perm (R7): FETCH at unique-bytes floor.
    const int nwg_per_xcd = (NBOX * CD) / NXCD;   // 512
    const int hwid = blockIdx.x;
    const int blk = (hwid & (NXCD - 1)) * nwg_per_xcd + (hwid >> 3);

    const int slot = blk >> 4;
    const int b = perm ? perm[slot] : slot;
    const int z = blk & 15;
    const int t  = threadIdx.x;
    const int ty = t >> 4;             // out-y == staged row id
    const int tx = t & 15;             // out-x == stage group id

    const float bx1 = boxes[b*6+0], by1 = boxes[b*6+1], bz1 = boxes[b*6+2];
    const float bx2 = boxes[b*6+3], by2 = boxes[b*6+4], bz2 = boxes[b*6+5];
    const int   n   = box_ind[b];

    const float zstep = (bz2 - bz1) * 63.0f / 15.0f;
    const float ystep = (by2 - by1) * 63.0f / 15.0f;
    const float xstep = (bx2 - bx1) * 63.0f / 15.0f;  // >= 0 (boxes sorted)

    // z (block-uniform)
    const float zc = bz1 * 63.0f + (float)z * zstep;
    const bool  vz = (zc >= 0.0f) && (zc <= 63.0f);
    const float zq = fminf(fmaxf(zc, 0.0f), 63.0f);
    const int   z0 = (int)floorf(zq);
    const int   z1 = min(z0 + 1, ND - 1);
    const float fz = zq - (float)z0;

    // y (this thread; also the staging row's y)
    const float yc = by1 * 63.0f + (float)ty * ystep;
    const bool  vy = (yc >= 0.0f) && (yc <= 63.0f);
    const float yq = fminf(fmaxf(yc, 0.0f), 63.0f);
    const int   y0 = (int)floorf(yq);
    const int   y1 = min(y0 + 1, NH - 1);
    const float fy = yq - (float)y0;

    // x (this thread)
    const float xcf = bx1 * 63.0f + (float)tx * xstep;
    const bool  vx  = (xcf >= 0.0f) && (xcf <= 63.0f);
    const float xq  = fminf(fmaxf(xcf, 0.0f), 63.0f);
    const int   x0  = (int)floorf(xq);
    const int   x1  = min(x0 + 1, NW - 1);
    const float fx  = xq - (float)x0;

    const bool valid = vz && vy && vx;
    const float gz = 1.0f - fz, gy = 1.0f - fy, gx = 1.0f - fx;

    // staging combine weights (z,y pre-interp; this thread's ty == its row)
    const float w00 = gz * gy, w01 = gz * fy, w10 = fz * gy, w11 = fz * fy;

    // x-window (block-uniform)
    const float xcl = bx1 * 63.0f;
    const float xch = bx1 * 63.0f + 15.0f * xstep;
    const int x0min = (int)floorf(fminf(fmaxf(xcl, 0.0f), 63.0f));
    const int xlo4  = x0min & ~3;                  // 4-aligned window start

    // staging source offsets (channel-invariant): 4 source rows, group tx.
    // Clamp sx so the 16B load never crosses the row end (clamped groups are
    // never read back: readers only touch dx <= 63-xlo4).
    const int sx = min(xlo4 + (tx << 2), NW - 4);
    const int soff0 = (z0 * NH + y0) * NW + sx;
    const int soff1 = (z0 * NH + y1) * NW + sx;
    const int soff2 = (z1 * NH + y0) * NW + sx;
    const int soff3 = (z1 * NH + y1) * NW + sx;

    // LDS addressing with per-row XOR swizzle: key = 2*q spreads the 4
    // q-groups of a wave across the 32 banks (breaks the 4-way conflict).
    const int key  = (ty & 3) << 1;
    const int wadr = ty * 64 + ((tx ^ key) << 2);  // ds_write_b128 slot (floats)
    const int dx0  = x0 - xlo4;
    const int dx1  = x1 - xlo4;
    const int a0   = ty * 64 + ((((dx0 >> 2) ^ key)) << 2) + (dx0 & 3);
    const int a1   = ty * 64 + ((((dx1 >> 2) ^ key)) << 2) + (dx1 & 3);

    const float* imgb = image + (size_t)n * (NC * DHW);
    float* op = out + (size_t)b * (NC * CD * CH * CW) + (z * CH + ty) * CW + tx;

    float4 A0, A1, A2, A3, B0, B1, B2, B3;

    #define ISSUE(Ra, Rb, Rc, Rd, c)  do {                                     \
        const float* p_ = imgb + (size_t)(c) * DHW;                            \
        Ra = *(const float4*)(p_ + soff0);                                     \
        Rb = *(const float4*)(p_ + soff1);                                     \
        Rc = *(const float4*)(p_ + soff2);                                     \
        Rd = *(const float4*)(p_ + soff3);                                     \
    } while (0)

    // combine 4 source rows with (z,y) weights and write one LDS row slot
    #define CWRITE(Ra, Rb, Rc, Rd, c)  do {                                    \
        float4 o_;                                                             \
        o_.x = Ra.x * w00 + Rb.x * w01 + Rc.x * w10 + Rd.x * w11;              \
        o_.y = Ra.y * w00 + Rb.y * w01 + Rc.y * w10 + Rd.y * w11;              \
        o_.z = Ra.z * w00 + Rb.z * w01 + Rc.z * w10 + Rd.z * w11;              \
        o_.w = Ra.w * w00 + Rb.w * w01 + Rc.w * w10 + Rd.w * w11;              \
        *(float4*)(sh + (((c) & 1) << 10) + wadr) = o_;                        \
    } while (0)

    #define COMPUTE(c)  do {                                                   \
        const float* S_ = sh + (((c) & 1) << 10);                              \
        const float s0 = S_[a0], s1 = S_[a1];                                  \
        float v = s0 * gx + s1 * fx;                                           \
        v = valid ? v : 0.0f;                                                  \
        __builtin_nontemporal_store(v, op + (c) * (CD * CH * CW));             \
    } while (0)

    // prologue
    ISSUE(A0, A1, A2, A3, 0);
    CWRITE(A0, A1, A2, A3, 0);         // compiler waits vmcnt for A
    ISSUE(B0, B1, B2, B3, 1);

    // steady state: issue c+2 early (T14), compute c from LDS, combine+write
    // c+1; one bare s_barrier per channel as phase governor.
    #pragma unroll
    for (int c = 0; c < NC; c += 2) {
        // even channel: regs A free after CWRITE(c) -> load c+2 into A
        if (c + 2 < NC) ISSUE(A0, A1, A2, A3, c + 2);
        COMPUTE(c);
        if (c + 1 < NC) CWRITE(B0, B1, B2, B3, c + 1);
        __builtin_amdgcn_s_barrier();
        // odd channel: regs B free -> load c+3 into B
        if (c + 1 < NC) {
            if (c + 3 < NC) ISSUE(B0, B1, B2, B3, c + 3);
            COMPUTE(c + 1);
            if (c + 2 < NC) CWRITE(A0, A1, A2, A3, c + 2);
            __builtin_amdgcn_s_barrier();
        }
    }

    #undef ISSUE
    #undef CWRITE
    #undef COMPUTE
}

extern "C" void kernel_launch(void* const* d_in, const int* in_sizes, int n_in,
                              void* d_out, int out_size, void* d_ws, size_t ws_size,
                              hipStream_t stream) {
    const float* image   = (const float*)d_in[0];
    const float* boxes   = (const float*)d_in[1];
    const int*   box_ind = (const int*)d_in[2];
    float*       out     = (float*)d_out;

    int* perm = nullptr;
    if (ws_size >= NBOX * sizeof(int)) {
        perm = (int*)d_ws;
        CropAndResize3D_perm_kernel<<<1, NBOX, 0, stream>>>(box_ind, perm);
    }

    const int blocks = NBOX * CD;  // 4096
    CropAndResize3D_89481348645400_kernel<<<blocks, 256, 0, stream>>>(
        image, boxes, box_ind, perm, out);
}

// Round 11
// 113.568 us; speedup vs baseline: 1.1372x; 1.1372x over previous
//
#include <hip/hip_runtime.h>
#include <stdint.h>

// Problem constants (from reference setup_inputs)
#define NBOX 256
#define NC   32
#define ND   64
#define NH   64
#define NW   64
#define CD   16
#define CH   16
#define CW   16
#define NXCD 8
#define DHW  (ND * NH * NW)
// LDS: 2 buffers x 16 rows x 64 floats = 8192 B.
// Row yo holds the (z,y)-PRE-COMBINED source row for output row yo:
//   comb[x] = w00*I[z0,y0,x] + w01*I[z0,y1,x] + w10*I[z1,y0,x] + w11*I[z1,y1,x]
// Stager == consumer (same 16-lane group) -> no barrier needed for
// correctness; one bare s_barrier per channel as phase governor (R9 lesson).

// ---- pre-kernel: stable counting-sort permutation of boxes by box_ind ----
__global__ __launch_bounds__(NBOX) void CropAndResize3D_perm_kernel(
    const int* __restrict__ box_ind, int* __restrict__ perm)
{
    __shared__ int nsh[NBOX];
    const int t = threadIdx.x;
    nsh[t] = box_ind[t];
    __syncthreads();
    const int n_t = nsh[t];
    int rank = 0;
    #pragma unroll 8
    for (int j = 0; j < NBOX; ++j) {
        const int n_j = nsh[j];
        rank += (n_j < n_t) || (n_j == n_t && j < t);
    }
    perm[rank] = t;
}

__global__ __launch_bounds__(256) void CropAndResize3D_89481348645400_kernel(
    const float* __restrict__ image,   // (N, C, D, H, W)
    const float* __restrict__ boxes,   // (NB, 6) = x1,y1,z1,x2,y2,z2
    const int*   __restrict__ box_ind, // (NB,)
    const int*   __restrict__ perm,    // (NB,) or null -> identity
    float*       __restrict__ out)     // (NB, C, CD, CH, CW)
{
    __shared__ float sh[2 * 16 * 64];  // 8 KB

    // XCD-aware swizzle (R1) + image-sorted perm (R7): FETCH at unique-bytes floor.
    const int nwg_per_xcd = (NBOX * CD) / NXCD;   // 512
    const int hwid = blockIdx.x;
    const int blk = (hwid & (NXCD - 1)) * nwg_per_xcd + (hwid >> 3);

    const int slot = blk >> 4;
    const int b = perm ? perm[slot] : slot;
    const int z = blk & 15;
    const int t  = threadIdx.x;
    const int ty = t >> 4;             // out-y == staged row id
    const int tx = t & 15;             // out-x == stage group id

    const float bx1 = boxes[b*6+0], by1 = boxes[b*6+1], bz1 = boxes[b*6+2];
    const float bx2 = boxes[b*6+3], by2 = boxes[b*6+4], bz2 = boxes[b*6+5];
    const int   n   = box_ind[b];

    const float zstep = (bz2 - bz1) * 63.0f / 15.0f;
    const float ystep = (by2 - by1) * 63.0f / 15.0f;
    const float xstep = (bx2 - bx1) * 63.0f / 15.0f;  // >= 0 (boxes sorted)

    // z (block-uniform)
    const float zc = bz1 * 63.0f + (float)z * zstep;
    const bool  vz = (zc >= 0.0f) && (zc <= 63.0f);
    const float zq = fminf(fmaxf(zc, 0.0f), 63.0f);
    const int   z0 = (int)floorf(zq);
    const int   z1 = min(z0 + 1, ND - 1);
    const float fz = zq - (float)z0;

    // y (this thread; also the staging row's y)
    const float yc = by1 * 63.0f + (float)ty * ystep;
    const bool  vy = (yc >= 0.0f) && (yc <= 63.0f);
    const float yq = fminf(fmaxf(yc, 0.0f), 63.0f);
    const int   y0 = (int)floorf(yq);
    const int   y1 = min(y0 + 1, NH - 1);
    const float fy = yq - (float)y0;

    // x (this thread)
    const float xcf = bx1 * 63.0f + (float)tx * xstep;
    const bool  vx  = (xcf >= 0.0f) && (xcf <= 63.0f);
    const float xq  = fminf(fmaxf(xcf, 0.0f), 63.0f);
    const int   x0  = (int)floorf(xq);
    const int   x1  = min(x0 + 1, NW - 1);
    const float fx  = xq - (float)x0;

    const bool valid = vz && vy && vx;
    const float gz = 1.0f - fz, gy = 1.0f - fy, gx = 1.0f - fx;

    // staging combine weights (z,y pre-interp; this thread's ty == its row)
    const float w00 = gz * gy, w01 = gz * fy, w10 = fz * gy, w11 = fz * fy;

    // x-window (block-uniform)
    const float xcl = bx1 * 63.0f;
    const float xch = bx1 * 63.0f + 15.0f * xstep;
    const int x0min = (int)floorf(fminf(fmaxf(xcl, 0.0f), 63.0f));
    const int x1max = min((int)floorf(fminf(fmaxf(xch, 0.0f), 63.0f)) + 1, NW - 1);
    const int xlo4  = x0min & ~3;                  // 4-aligned window start
    const int G     = ((x1max - xlo4) >> 2) + 1;   // touched groups, 1..16

    // R10 bug-fix: predicate staging to the G touched groups only.
    // (Active lanes have group start <= 60, so the min() clamp never fires
    // for them -> staged values are exactly R10's.)
    const bool act = (tx < G);

    // staging source offsets (channel-invariant): 4 source rows, group tx
    const int sx = min(xlo4 + (tx << 2), NW - 4);
    const int soff0 = (z0 * NH + y0) * NW + sx;
    const int soff1 = (z0 * NH + y1) * NW + sx;
    const int soff2 = (z1 * NH + y0) * NW + sx;
    const int soff3 = (z1 * NH + y1) * NW + sx;

    // LDS addressing with per-row XOR swizzle (key = 2*q): breaks the 4-way
    // cross-q bank conflict (R10: conflicts 7.8M -> 1.95M).
    const int key  = (ty & 3) << 1;
    const int wadr = ty * 64 + ((tx ^ key) << 2);
    const int dx0  = x0 - xlo4;
    const int dx1  = x1 - xlo4;
    const int a0   = ty * 64 + ((((dx0 >> 2) ^ key)) << 2) + (dx0 & 3);
    const int a1   = ty * 64 + ((((dx1 >> 2) ^ key)) << 2) + (dx1 & 3);

    const float* imgb = image + (size_t)n * (NC * DHW);
    float* op = out + (size_t)b * (NC * CD * CH * CW) + (z * CH + ty) * CW + tx;

    float4 A0 = {0,0,0,0}, A1 = {0,0,0,0}, A2 = {0,0,0,0}, A3 = {0,0,0,0};
    float4 B0 = {0,0,0,0}, B1 = {0,0,0,0}, B2 = {0,0,0,0}, B3 = {0,0,0,0};
    float4 C0 = {0,0,0,0}, C1 = {0,0,0,0}, C2 = {0,0,0,0}, C3 = {0,0,0,0};
    float4 D0 = {0,0,0,0}, D1 = {0,0,0,0}, D2 = {0,0,0,0}, D3 = {0,0,0,0};

    #define ISSUE(Ra, Rb, Rc, Rd, c)  do { if (act) {                          \
        const float* p_ = imgb + (size_t)(c) * DHW;                            \
        Ra = *(const float4*)(p_ + soff0);                                     \
        Rb = *(const float4*)(p_ + soff1);                                     \
        Rc = *(const float4*)(p_ + soff2);                                     \
        Rd = *(const float4*)(p_ + soff3); } } while (0)

    #define CWRITE(Ra, Rb, Rc, Rd, c)  do {                                    \
        float4 o_;                                                             \
        o_.x = Ra.x * w00 + Rb.x * w01 + Rc.x * w10 + Rd.x * w11;              \
        o_.y = Ra.y * w00 + Rb.y * w01 + Rc.y * w10 + Rd.y * w11;              \
        o_.z = Ra.z * w00 + Rb.z * w01 + Rc.z * w10 + Rd.z * w11;              \
        o_.w = Ra.w * w00 + Rb.w * w01 + Rc.w * w10 + Rd.w * w11;              \
        *(float4*)(sh + (((c) & 1) << 10) + wadr) = o_;                        \
    } while (0)

    #define COMPUTE(c)  do {                                                   \
        const float* S_ = sh + (((c) & 1) << 10);                              \
        const float s0 = S_[a0], s1 = S_[a1];                                  \
        float v = s0 * gx + s1 * fx;                                           \
        v = valid ? v : 0.0f;                                                  \
        __builtin_nontemporal_store(v, op + (c) * (CD * CH * CW));             \
    } while (0)

    // depth-4 register pipeline: prefetch distance = 4 channel-phases
    ISSUE(A0, A1, A2, A3, 0);
    ISSUE(B0, B1, B2, B3, 1);
    ISSUE(C0, C1, C2, C3, 2);
    ISSUE(D0, D1, D2, D3, 3);

    #pragma unroll
    for (int c = 0; c < NC; c += 4) {
        CWRITE(A0, A1, A2, A3, c    );  COMPUTE(c    );
        if (c + 4 < NC) ISSUE(A0, A1, A2, A3, c + 4);
        __builtin_amdgcn_s_barrier();

        CWRITE(B0, B1, B2, B3, c + 1);  COMPUTE(c + 1);
        if (c + 5 < NC) ISSUE(B0, B1, B2, B3, c + 5);
        __builtin_amdgcn_s_barrier();

        CWRITE(C0, C1, C2, C3, c + 2);  COMPUTE(c + 2);
        if (c + 6 < NC) ISSUE(C0, C1, C2, C3, c + 6);
        __builtin_amdgcn_s_barrier();

        CWRITE(D0, D1, D2, D3, c + 3);  COMPUTE(c + 3);
        if (c + 7 < NC) ISSUE(D0, D1, D2, D3, c + 7);
        __builtin_amdgcn_s_barrier();
    }

    #undef ISSUE
    #undef CWRITE
    #undef COMPUTE
}

extern "C" void kernel_launch(void* const* d_in, const int* in_sizes, int n_in,
                              void* d_out, int out_size, void* d_ws, size_t ws_size,
                              hipStream_t stream) {
    const float* image   = (const float*)d_in[0];
    const float* boxes   = (const float*)d_in[1];
    const int*   box_ind = (const int*)d_in[2];
    float*       out     = (float*)d_out;

    int* perm = nullptr;
    if (ws_size >= NBOX * sizeof(int)) {
        perm = (int*)d_ws;
        CropAndResize3D_perm_kernel<<<1, NBOX, 0, stream>>>(box_ind, perm);
    }

    const int blocks = NBOX * CD;  // 4096
    CropAndResize3D_89481348645400_kernel<<<blocks, 256, 0, stream>>>(
        image, boxes, box_ind, perm, out);
}

// Round 12
// 112.217 us; speedup vs baseline: 1.1509x; 1.0120x over previous
//
#include <hip/hip_runtime.h>
#include <stdint.h>

// Problem constants (from reference setup_inputs)
#define NBOX 256
#define NC   32
#define ND   64
#define NH   64
#define NW   64
#define CD   16
#define CH   16
#define CW   16
#define NXCD 8
#define DHW  (ND * NH * NW)
// LDS: 2 buffers x 64 rows x 64 floats = 32768 B -> 5 blocks/CU
//
// R12 = revert to R7 (best: 112.0 us). Rationale: effective HBM throughput
// is invariant at 3.6-3.8 TB/s across 8 structurally diverse schedules
// (R2,R4,R6,R7,R9,R10,R11) -> memory-system ceiling for this scattered-
// segment read + streaming write mix. R7 has both byte streams at their
// floors (FETCH ~= image unique bytes, WRITE = output) and the best rate.

// ---- pre-kernel: stable counting-sort permutation of boxes by box_ind ----
__global__ __launch_bounds__(NBOX) void CropAndResize3D_perm_kernel(
    const int* __restrict__ box_ind, int* __restrict__ perm)
{
    __shared__ int nsh[NBOX];
    const int t = threadIdx.x;
    nsh[t] = box_ind[t];
    __syncthreads();
    const int n_t = nsh[t];
    int rank = 0;
    #pragma unroll 8
    for (int j = 0; j < NBOX; ++j) {
        const int n_j = nsh[j];
        rank += (n_j < n_t) || (n_j == n_t && j < t);
    }
    perm[rank] = t;
}

__global__ __launch_bounds__(256) void CropAndResize3D_89481348645400_kernel(
    const float* __restrict__ image,   // (N, C, D, H, W)
    const float* __restrict__ boxes,   // (NB, 6) = x1,y1,z1,x2,y2,z2
    const int*   __restrict__ box_ind, // (NB,)
    const int*   __restrict__ perm,    // (NB,) or null -> identity
    float*       __restrict__ out)     // (NB, C, CD, CH, CW)
{
    __shared__ float sh[2 * 64 * 64];

    // XCD-aware swizzle (R1 win) + image-sorted perm (R7 win):
    // FETCH at unique-bytes floor.
    const int nwg_per_xcd = (NBOX * CD) / NXCD;   // 512
    const int hw  = blockIdx.x;
    const int blk = (hw & (NXCD - 1)) * nwg_per_xcd + (hw >> 3);

    const int slot = blk >> 4;         // logical (sorted) box slot
    const int b = perm ? perm[slot] : slot;  // actual box id
    const int z = blk & 15;            // crop depth index
    const int t  = threadIdx.x;
    const int ty = t >> 4;             // out-y
    const int tx = t & 15;             // out-x / stage slot id

    const float bx1 = boxes[b*6+0], by1 = boxes[b*6+1], bz1 = boxes[b*6+2];
    const float bx2 = boxes[b*6+3], by2 = boxes[b*6+4], bz2 = boxes[b*6+5];
    const int   n   = box_ind[b];

    const float zstep = (bz2 - bz1) * 63.0f / 15.0f;
    const float ystep = (by2 - by1) * 63.0f / 15.0f;
    const float xstep = (bx2 - bx1) * 63.0f / 15.0f;  // >= 0 (boxes sorted)

    // z (block-uniform)
    const float zc = bz1 * 63.0f + (float)z * zstep;
    const bool  vz = (zc >= 0.0f) && (zc <= 63.0f);
    const float zq = fminf(fmaxf(zc, 0.0f), 63.0f);
    const int   z0 = (int)floorf(zq);
    const int   z1 = min(z0 + 1, ND - 1);
    const float fz = zq - (float)z0;

    // y (this thread)
    const float yc = by1 * 63.0f + (float)ty * ystep;
    const bool  vy = (yc >= 0.0f) && (yc <= 63.0f);
    const float yq = fminf(fmaxf(yc, 0.0f), 63.0f);
    const float fy = yq - floorf(yq);

    // x (this thread)
    const float xcf = bx1 * 63.0f + (float)tx * xstep;
    const bool  vx  = (xcf >= 0.0f) && (xcf <= 63.0f);
    const float xq  = fminf(fmaxf(xcf, 0.0f), 63.0f);
    const int   x0  = (int)floorf(xq);
    const int   x1  = min(x0 + 1, NW - 1);
    const float fx  = xq - (float)x0;

    const bool valid = vz && vy && vx;
    const float gz = 1.0f - fz, gy = 1.0f - fy, gx = 1.0f - fx;

    // x-window (block-uniform; xc monotone in tx since xstep >= 0)
    const float xcl = bx1 * 63.0f;
    const float xch = bx1 * 63.0f + 15.0f * xstep;
    const int x0min = (int)floorf(fminf(fmaxf(xcl, 0.0f), 63.0f));
    const int x1max = min((int)floorf(fminf(fmaxf(xch, 0.0f), 63.0f)) + 1, NW - 1);
    const int xlo4  = x0min & ~3;                  // 4-aligned window start
    const int G     = ((x1max - xlo4) >> 2) + 1;   // float4 groups, 1..16

    // staging (DMA): row r = zcorner*32 + yo*2 + ycorner; slot s holds global
    // group s ^ (r&7) [pre-swizzled SOURCE, linear LDS dest per rule #21].
    const int key = ty & 7;                        // == r&7 for r = k*16+ty
    const bool act = ((tx ^ key) < G);             // G active slots per row
    const int sx  = xlo4 + ((tx ^ key) << 2);      // swizzled global x start

    int soff0, soff1, soff2, soff3;
    {
        int tmp[4];
        #pragma unroll
        for (int k = 0; k < 4; ++k) {
            const int r   = k * 16 + ty;
            const int yo  = (r >> 1) & 15;
            const int yc_ = r & 1;
            const int zs  = (r >> 5) ? z1 : z0;
            const float yco = by1 * 63.0f + (float)yo * ystep;
            const float yqs = fminf(fmaxf(yco, 0.0f), 63.0f);
            const int   ys0 = (int)floorf(yqs);
            const int   ysel = yc_ ? min(ys0 + 1, NH - 1) : ys0;
            tmp[k] = (zs * NH + ysel) * NW + sx;
        }
        soff0 = tmp[0]; soff1 = tmp[1]; soff2 = tmp[2]; soff3 = tmp[3];
    }
    // wave-uniform LDS float offsets for the 4 DMA calls
    const int wb    = (ty & ~3) * 64;              // wave base row * 64
    const int ldsb0 = wb;
    const int ldsb1 = wb + 16 * 64;
    const int ldsb2 = wb + 32 * 64;
    const int ldsb3 = wb + 48 * 64;

    // compute-side swizzled LDS read addresses (channel-invariant)
    const int dx0 = x0 - xlo4;
    const int dx1 = x1 - xlo4;
    #define IDX(r, dx) ((r) * 64 + (((((dx) >> 2) ^ ((r) & 7))) << 2) + ((dx) & 3))
    const int a000 = IDX(2*ty    , dx0), a001 = IDX(2*ty    , dx1);
    const int a010 = IDX(2*ty + 1, dx0), a011 = IDX(2*ty + 1, dx1);
    const int a100 = IDX(32+2*ty , dx0), a101 = IDX(32+2*ty , dx1);
    const int a110 = IDX(33+2*ty , dx0), a111 = IDX(33+2*ty , dx1);
    #undef IDX

    const float* imgb = image + (size_t)n * (NC * DHW);
    float* op = out + (size_t)b * (NC * CD * CH * CW) + (z * CH + ty) * CW + tx;

    #define ISSUE(c)  do { if (act) {                                          \
        const float* p_ = imgb + (size_t)(c) * DHW;                            \
        float* l_ = sh + (((c) & 1) << 12);                                    \
        __builtin_amdgcn_global_load_lds(                                      \
            (const __attribute__((address_space(1))) uint32_t*)(p_ + soff0),   \
            (__attribute__((address_space(3))) uint32_t*)(l_ + ldsb0), 16, 0, 0); \
        __builtin_amdgcn_global_load_lds(                                      \
            (const __attribute__((address_space(1))) uint32_t*)(p_ + soff1),   \
            (__attribute__((address_space(3))) uint32_t*)(l_ + ldsb1), 16, 0, 0); \
        __builtin_amdgcn_global_load_lds(                                      \
            (const __attribute__((address_space(1))) uint32_t*)(p_ + soff2),   \
            (__attribute__((address_space(3))) uint32_t*)(l_ + ldsb2), 16, 0, 0); \
        __builtin_amdgcn_global_load_lds(                                      \
            (const __attribute__((address_space(1))) uint32_t*)(p_ + soff3),   \
            (__attribute__((address_space(3))) uint32_t*)(l_ + ldsb3), 16, 0, 0); \
    } } while (0)

    #define COMPUTE(c)  do {                                                   \
        const float* S_ = sh + (((c) & 1) << 12);                              \
        const float s000 = S_[a000], s001 = S_[a001];                          \
        const float s010 = S_[a010], s011 = S_[a011];                          \
        const float s100 = S_[a100], s101 = S_[a101];                          \
        const float s110 = S_[a110], s111 = S_[a111];                          \
        const float c00 = s000 * gx + s001 * fx;                               \
        const float c01 = s010 * gx + s011 * fx;                               \
        const float c10 = s100 * gx + s101 * fx;                               \
        const float c11 = s110 * gx + s111 * fx;                               \
        const float c0  = c00 * gy + c01 * fy;                                 \
        const float c1  = c10 * gy + c11 * fy;                                 \
        float v = c0 * gz + c1 * fz;                                           \
        v = valid ? v : 0.0f;                                                  \
        __builtin_nontemporal_store(v, op + (c) * (CD * CH * CW));             \
    } while (0)

    // prologue: ch0 -> buf0, ch1 -> buf1; wait ch0 (keep ch1 in flight)
    ISSUE(0);
    ISSUE(1);
    asm volatile("s_waitcnt vmcnt(4)" ::: "memory");
    __builtin_amdgcn_s_barrier();
    __builtin_amdgcn_sched_barrier(0);

    #pragma unroll 2
    for (int c = 0; c < NC; ++c) {
        COMPUTE(c);
        if (c + 1 < NC) {
            __builtin_amdgcn_sched_barrier(0);
            __builtin_amdgcn_s_barrier();           // buf[c&1] free for overwrite
            __builtin_amdgcn_sched_barrier(0);
            if (c + 2 < NC) {
                ISSUE(c + 2);                       // -> buf[c&1]
                asm volatile("s_waitcnt vmcnt(4)" ::: "memory");  // drain c+1
            } else {
                asm volatile("s_waitcnt vmcnt(0)" ::: "memory");  // tail drain
            }
            __builtin_amdgcn_sched_barrier(0);
            __builtin_amdgcn_s_barrier();           // all waves' c+1 rows visible
            __builtin_amdgcn_sched_barrier(0);
        }
    }

    #undef ISSUE
    #undef COMPUTE
}

extern "C" void kernel_launch(void* const* d_in, const int* in_sizes, int n_in,
                              void* d_out, int out_size, void* d_ws, size_t ws_size,
                              hipStream_t stream) {
    const float* image   = (const float*)d_in[0];
    const float* boxes   = (const float*)d_in[1];
    const int*   box_ind = (const int*)d_in[2];
    float*       out     = (float*)d_out;

    int* perm = nullptr;
    if (ws_size >= NBOX * sizeof(int)) {
        perm = (int*)d_ws;
        CropAndResize3D_perm_kernel<<<1, NBOX, 0, stream>>>(box_ind, perm);
    }

    const int blocks = NBOX * CD;  // 4096
    CropAndResize3D_89481348645400_kernel<<<blocks, 256, 0, stream>>>(
        image, boxes, box_ind, perm, out);
}